// Round 1
// 180.375 us; speedup vs baseline: 1.0689x; 1.0689x over previous
//
#include <hip/hip_runtime.h>

// SimpleGraphSAGE on MI355X — round 12.
// dst = repeat(arange(N),16) -> node i's edges are src[16i..16i+16), deg==16.
//
// History: R8 fused+sorted 66us/layer; R9 spill regression (launch_bounds
// too tight); R10 packed-LDS + (256,4): 61us/layer; R11 fp8-e4m3 gather
// tables -> 64B rows (1 line), 192.8us total, absmax 0.0078 (thr 0.0188).
// Cost model: ~20 cyc per distinct random row per CU + ~2.5 cyc per 64B line.
// R12 theory: part of the per-row cost is per-LANE address processing.
// Gather restructure: 4 lanes x dwordx4 (16B) per 64B row instead of
// 8 lanes x uint2 (8B). Same cache lines, half the lane-addresses and half
// the gather load instructions; one sort16 per lane instead of two; half
// the redundant src-index loads; ~16 VGPRs freed for deeper load pipelining.

#define NN   100000
#define DEG  16
#define F    64
#define NPB  64           // nodes per block (256 threads, 4 waves)
#define STR  65           // LDS column stride (+1 pad)
#define JPW  16           // output columns per wave
#define EDG  (NN * DEG)

#if __has_builtin(__builtin_amdgcn_cvt_pk_f32_fp8) && __has_builtin(__builtin_amdgcn_cvt_pk_fp8_f32)
#define HW_FP8 1
#else
#define HW_FP8 0
#endif

typedef float v2f __attribute__((ext_vector_type(2)));

__device__ __forceinline__ ushort f2bf(float f) {        // RNE
    unsigned u = __float_as_uint(f);
    return (ushort)((u + 0x7fffu + ((u >> 16) & 1u)) >> 16);
}
__device__ __forceinline__ float bf2f(ushort u) {
    return __uint_as_float(((unsigned)u) << 16);
}

// ---- fp8 e4m3 helpers (HW path on gfx950; manual RNE fallback) ----
#if !HW_FP8
__device__ __forceinline__ unsigned fp8_enc1(float f) {  // e4m3fn RNE, saturating
    const unsigned u = __float_as_uint(f);
    const unsigned s = (u >> 31) << 7;
    const float af = fabsf(f);
    if (!(af < 448.f)) return s | 0x7E;                  // sat (also NaN->max)
    if (af < 0.015625f) {                                // subnormal, step 2^-9
        const int n = (int)rintf(af * 512.f);            // 0..8 (8 -> min normal)
        return s | (unsigned)n;
    }
    unsigned au = u & 0x7FFFFFFFu;
    const unsigned lsb = (au >> 20) & 1u;
    au += 0x7FFFFu + lsb;                                // RNE at bit 20
    const int e = (int)(au >> 23) - 127;
    if (e > 8) return s | 0x7E;
    return s | ((unsigned)(e + 7) << 3) | ((au >> 20) & 7u);
}
__device__ __forceinline__ float fp8_dec1(unsigned c) {
    const unsigned s = c >> 7;
    const int e = (int)((c >> 3) & 15u);
    const unsigned m = c & 7u;
    const float v = e ? ldexpf((float)(8 + m), e - 10) : ldexpf((float)m, -9);
    return s ? -v : v;
}
#endif

// pack 4 floats -> 4 fp8 bytes in one dword
__device__ __forceinline__ unsigned fp8_pack4(float a, float b, float c, float d) {
#if HW_FP8
    int t = __builtin_amdgcn_cvt_pk_fp8_f32(a, b, 0, false);
    t     = __builtin_amdgcn_cvt_pk_fp8_f32(c, d, t, true);
    return (unsigned)t;
#else
    return fp8_enc1(a) | (fp8_enc1(b) << 8) | (fp8_enc1(c) << 16) | (fp8_enc1(d) << 24);
#endif
}

// accumulate 4 fp8 bytes (one dword) into acc[0..3]
__device__ __forceinline__ void fp8_acc4(unsigned d, float* acc) {
#if HW_FP8
    const v2f lo = __builtin_amdgcn_cvt_pk_f32_fp8((int)d, false);
    const v2f hi = __builtin_amdgcn_cvt_pk_f32_fp8((int)d, true);
    acc[0] += lo.x; acc[1] += lo.y; acc[2] += hi.x; acc[3] += hi.y;
#else
    acc[0] += fp8_dec1(d & 0xffu);
    acc[1] += fp8_dec1((d >> 8) & 0xffu);
    acc[2] += fp8_dec1((d >> 16) & 0xffu);
    acc[3] += fp8_dec1(d >> 24);
#endif
}

// x (fp32) -> fp8 gather table
__global__ __launch_bounds__(256)
void cvt_f32_fp8(const float* __restrict__ in, unsigned* __restrict__ out, int n4)
{
    int i = blockIdx.x * 256 + threadIdx.x;
    if (i < n4) {
        float4 v = ((const float4*)in)[i];
        out[i] = fp8_pack4(v.x, v.y, v.z, v.w);
    }
}

// Batcher odd-even mergesort, 16 keys, fully unrolled -> registers only.
__device__ __forceinline__ void ce(unsigned& a, unsigned& b) {
    const unsigned lo = min(a, b), hi = max(a, b); a = lo; b = hi;
}
__device__ __forceinline__ void sort16(unsigned s[16]) {
    #pragma unroll
    for (int p = 1; p < 16; p <<= 1) {
        #pragma unroll
        for (int k = p; k >= 1; k >>= 1) {
            #pragma unroll
            for (int j = k & (p - 1); j + k < 16; j += 2 * k) {
                #pragma unroll
                for (int i = 0; i < k; ++i) {
                    if (i + j + k < 16)
                        if ((i + j) / (2 * p) == (i + j + k) / (2 * p))
                            ce(s[i + j], s[i + j + k]);
                }
            }
        }
    }
}

// ---------------- fused layer: sorted fp8 gather + SGPR-W matmul ----------------
// bufA[f][n]: fp32 self features (exact path).
// bufB[kk][n]: neighbor-mean bf16 pair (features 2kk,2kk+1 of the mean half).
template<bool RELU, bool SELF_F32, bool EMIT_F32>
__global__ __launch_bounds__(256, 4)
void sage_fused(const float*  __restrict__ selfA,      // [NN,F] fp32 (if SELF_F32)
                const ushort* __restrict__ selfB,      // [NN,F] bf16 (else)
                const unsigned char* __restrict__ gat, // [NN,F] fp8 table
                const float*  __restrict__ W,          // [2F,F]
                const float*  __restrict__ bias,       // [F]
                const int*    __restrict__ src,        // [EDG]
                float*        __restrict__ out_f32,    // if EMIT_F32
                ushort*       __restrict__ out_bf16,   // else: h table (self)
                unsigned char* __restrict__ out_fp8)   // else: h table (gather)
{
    __shared__ float    bufA[F][STR];        // 16.64 KB
    __shared__ unsigned bufB[F / 2][STR];    //  8.32 KB   (25 KB total)

    const int tid   = threadIdx.x;
    const int lane  = tid & 63;
    const int wave  = __builtin_amdgcn_readfirstlane(tid >> 6);
    const int node0 = blockIdx.x * NPB;

    // ---- Self staging: lane = feature, wave stages its 16 nodes ----
    #pragma unroll 4
    for (int m = 0; m < JPW; ++m) {
        const int n    = wave * JPW + m;
        const int node = node0 + n;
        float v = 0.f;
        if (node < NN)
            v = SELF_F32 ? selfA[(size_t)node * F + lane]
                         : bf2f(selfB[(size_t)node * F + lane]);
        bufA[lane][n] = v;
    }

    // ---- Sorted fp8 gather: 4-lane group handles ONE node; dwordx4 rows ----
    // Row = 64B fp8 = one cache line: 4 lanes x 16B. Half the lane-addresses
    // per row and half the load instructions vs the 8-lane/uint2 scheme (R12).
    {
        const int q     = lane & 3;          // features 16q .. 16q+15
        const int g     = lane >> 2;         // node within wave
        const int nloc  = wave * JPW + g;
        const int n     = node0 + nloc;
        const bool v    = n < NN;

        unsigned s[DEG];
        {
            const int4* p = (const int4*)(src + (size_t)n * DEG);
            #pragma unroll
            for (int t = 0; t < 4; ++t) {
                const int4 a = v ? p[t] : make_int4(0, 0, 0, 0);
                s[4*t+0] = a.x; s[4*t+1] = a.y;
                s[4*t+2] = a.z; s[4*t+3] = a.w;
            }
        }
        sort16(s);

        float a[16];
        #pragma unroll
        for (int f = 0; f < 16; ++f) a[f] = 0.f;

        #pragma unroll
        for (int e = 0; e < DEG; ++e) {
            // one 16B load per lane; 4 lanes cover the 64B row (1 line)
            const uint4 r = *(const uint4*)(gat + (size_t)s[e] * F + q * 16);
            fp8_acc4(r.x, a);
            fp8_acc4(r.y, a + 4);
            fp8_acc4(r.z, a + 8);
            fp8_acc4(r.w, a + 12);
        }

        // Mean -> packed bf16 pairs; kk = 8q + t covers features 16q+2t, +1.
        #pragma unroll
        for (int t = 0; t < 8; ++t) {
            const unsigned d =
                (unsigned)f2bf(a[2*t]     * (1.0f / DEG)) |
                ((unsigned)f2bf(a[2*t+1]  * (1.0f / DEG)) << 16);
            bufB[8 * q + t][nloc] = d;   // bank = (8q+t+g)%32 -> 2-way, free
        }
    }
    __syncthreads();

    // ---- Matmul: lane = node, wave owns j in [16w,16w+16) ----
    const int j0 = wave * JPW;
    float acc[JPW];
    #pragma unroll
    for (int j = 0; j < JPW; ++j) acc[j] = bias[j0 + j];   // s_load

    // Self half (fp32 LDS, exact)
    #pragma unroll 4
    for (int k = 0; k < F; ++k) {
        const float v = bufA[k][lane];           // ds_read_b32, 2-way = free
        const float* Wr = W + k * F + j0;        // wave-uniform -> s_load
        #pragma unroll
        for (int j = 0; j < JPW; ++j)
            acc[j] = fmaf(v, Wr[j], acc[j]);
    }
    // Neighbor half (packed bf16 pairs)
    #pragma unroll 2
    for (int kk = 0; kk < F / 2; ++kk) {
        const unsigned d = bufB[kk][lane];
        const float vlo = __uint_as_float(d << 16);
        const float vhi = __uint_as_float(d & 0xffff0000u);
        const float* Wlo = W + (F + 2 * kk)     * F + j0;
        const float* Whi = W + (F + 2 * kk + 1) * F + j0;
        #pragma unroll
        for (int j = 0; j < JPW; ++j) {
            acc[j] = fmaf(vlo, Wlo[j], acc[j]);
            acc[j] = fmaf(vhi, Whi[j], acc[j]);
        }
    }

    const int node = node0 + lane;
    if (node < NN) {
        if (RELU) {
            #pragma unroll
            for (int j = 0; j < JPW; ++j) acc[j] = fmaxf(acc[j], 0.f);
        }
        if (EMIT_F32) {
            float4* op = (float4*)(out_f32 + (size_t)node * F + j0);
            #pragma unroll
            for (int t = 0; t < 4; ++t)
                op[t] = make_float4(acc[4 * t], acc[4 * t + 1],
                                    acc[4 * t + 2], acc[4 * t + 3]);
        } else {
            // h tables: bf16 (self path of layer 2) + fp8 (gather table)
            uint4 q0, q1;
            #pragma unroll
            for (int t = 0; t < 8; ++t)
                (t < 4 ? (&q0.x)[t] : (&q1.x)[t - 4]) =
                    (unsigned)f2bf(acc[2 * t]) |
                    ((unsigned)f2bf(acc[2 * t + 1]) << 16);
            uint4* ob = (uint4*)(out_bf16 + (size_t)node * F + j0);
            ob[0] = q0; ob[1] = q1;

            uint4 p;
            #pragma unroll
            for (int t = 0; t < 4; ++t)
                (&p.x)[t] = fp8_pack4(acc[4*t], acc[4*t+1], acc[4*t+2], acc[4*t+3]);
            *(uint4*)(out_fp8 + (size_t)node * F + j0) = p;
        }
    }
}

// ---------------- fallback (round-3, all-fp32, fused) ----------------
template<bool RELU>
__global__ __launch_bounds__(256, 4)
void sage_layer_f32(const float* __restrict__ feat,
                    const float* __restrict__ W,
                    const float* __restrict__ bias,
                    const int*   __restrict__ src,
                    float*       __restrict__ out)
{
    __shared__ float buf[2 * F][STR];
    const int tid   = threadIdx.x;
    const int lane  = tid & 63;
    const int wave  = __builtin_amdgcn_readfirstlane(tid >> 6);
    const int node0 = blockIdx.x * NPB;

    #pragma unroll 2
    for (int m = 0; m < NPB / 4; ++m) {
        const int n    = wave * (NPB / 4) + m;
        const int node = node0 + n;
        if (node < NN) {
            buf[lane][n] = feat[node * F + lane];
            const int* sp = src + node * DEG;
            float s = 0.f;
            #pragma unroll
            for (int e = 0; e < DEG; ++e) s += feat[sp[e] * F + lane];
            buf[F + lane][n] = s * (1.0f / DEG);
        }
    }
    __syncthreads();

    const int j0 = wave * JPW;
    float acc[JPW];
    #pragma unroll
    for (int j = 0; j < JPW; ++j) acc[j] = bias[j0 + j];
    #pragma unroll 4
    for (int k = 0; k < 2 * F; ++k) {
        const float v = buf[k][lane];
        const float* Wr = W + k * F + j0;
        #pragma unroll
        for (int j = 0; j < JPW; ++j) acc[j] = fmaf(v, Wr[j], acc[j]);
    }
    const int node = node0 + lane;
    if (node < NN) {
        float4* op = (float4*)(out + node * F + j0);
        #pragma unroll
        for (int t = 0; t < 4; ++t) {
            float4 r = make_float4(acc[4 * t], acc[4 * t + 1],
                                   acc[4 * t + 2], acc[4 * t + 3]);
            if (RELU) {
                r.x = fmaxf(r.x, 0.f); r.y = fmaxf(r.y, 0.f);
                r.z = fmaxf(r.z, 0.f); r.w = fmaxf(r.w, 0.f);
            }
            op[t] = r;
        }
    }
}

extern "C" void kernel_launch(void* const* d_in, const int* in_sizes, int n_in,
                              void* d_out, int out_size, void* d_ws, size_t ws_size,
                              hipStream_t stream) {
    const float* x   = (const float*)d_in[0];
    const float* W1  = (const float*)d_in[1];
    const float* b1  = (const float*)d_in[2];
    const float* W2  = (const float*)d_in[3];
    const float* b2  = (const float*)d_in[4];
    const int*   src = (const int*)d_in[5];

    float* out = (float*)d_out;
    const int blocks = (NN + NPB - 1) / NPB;   // 1563

    const size_t hFP8 = (size_t)NN * F;                   //  6.4 MB
    const size_t hBF  = (size_t)NN * F * sizeof(ushort);  // 12.8 MB

    if (ws_size >= 2 * hFP8 + hBF) {
        unsigned char* x_fp8 = (unsigned char*)d_ws;
        ushort*        h_bf  = (ushort*)((char*)d_ws + hFP8);
        unsigned char* h_fp8 = (unsigned char*)d_ws + hFP8 + hBF;

        const int n4 = NN * F / 4;
        cvt_f32_fp8<<<(n4 + 255) / 256, 256, 0, stream>>>(x, (unsigned*)x_fp8, n4);
        sage_fused<true,  true,  false><<<blocks, 256, 0, stream>>>(
            x, nullptr, x_fp8, W1, b1, src, nullptr, h_bf, h_fp8);
        sage_fused<false, false, true ><<<blocks, 256, 0, stream>>>(
            nullptr, h_bf, h_fp8, W2, b2, src, out, nullptr, nullptr);
    } else {
        float* h = (float*)d_ws;
        sage_layer_f32<true ><<<blocks, 256, 0, stream>>>(x, W1, b1, src, h);
        sage_layer_f32<false><<<blocks, 256, 0, stream>>>(h, W2, b2, src, out);
    }
}

// Round 2
// 180.138 us; speedup vs baseline: 1.0704x; 1.0013x over previous
//
#include <hip/hip_runtime.h>

// SimpleGraphSAGE on MI355X — round 13.
// dst = repeat(arange(N),16) -> node i's edges are src[16i..16i+16), deg==16.
//
// History: R10 packed-LDS: 61us/layer; R11 fp8-e4m3 gather tables (64B rows):
// 70us/layer? -> measured 70; R12 gather restructure 4 lanes x dwordx4 per row:
// 49us/layer, 180.4us total, VGPR 40, bank conflicts 0.
// Cost model (fit R11->R12): ~11 cyc/row fixed + ~2 cyc per lane-address.
// R13 theory: the "fixed" 11 cyc is EXPOSED LATENCY, not TA throughput.
// VGPR=40 means only ~2-3 of the 16 gather loads are in flight per lane.
// Split gather into load-all-16 (reg array, +64 VGPR) then decode phase ->
// 16 outstanding random-line loads per lane. If latency-bound: ~35-40us/layer.
// If null: gather TA machinery is the roofline.

#define NN   100000
#define DEG  16
#define F    64
#define NPB  64           // nodes per block (256 threads, 4 waves)
#define STR  65           // LDS column stride (+1 pad)
#define JPW  16           // output columns per wave
#define EDG  (NN * DEG)

#if __has_builtin(__builtin_amdgcn_cvt_pk_f32_fp8) && __has_builtin(__builtin_amdgcn_cvt_pk_fp8_f32)
#define HW_FP8 1
#else
#define HW_FP8 0
#endif

typedef float v2f __attribute__((ext_vector_type(2)));

__device__ __forceinline__ ushort f2bf(float f) {        // RNE
    unsigned u = __float_as_uint(f);
    return (ushort)((u + 0x7fffu + ((u >> 16) & 1u)) >> 16);
}
__device__ __forceinline__ float bf2f(ushort u) {
    return __uint_as_float(((unsigned)u) << 16);
}

// ---- fp8 e4m3 helpers (HW path on gfx950; manual RNE fallback) ----
#if !HW_FP8
__device__ __forceinline__ unsigned fp8_enc1(float f) {  // e4m3fn RNE, saturating
    const unsigned u = __float_as_uint(f);
    const unsigned s = (u >> 31) << 7;
    const float af = fabsf(f);
    if (!(af < 448.f)) return s | 0x7E;                  // sat (also NaN->max)
    if (af < 0.015625f) {                                // subnormal, step 2^-9
        const int n = (int)rintf(af * 512.f);            // 0..8 (8 -> min normal)
        return s | (unsigned)n;
    }
    unsigned au = u & 0x7FFFFFFFu;
    const unsigned lsb = (au >> 20) & 1u;
    au += 0x7FFFFu + lsb;                                // RNE at bit 20
    const int e = (int)(au >> 23) - 127;
    if (e > 8) return s | 0x7E;
    return s | ((unsigned)(e + 7) << 3) | ((au >> 20) & 7u);
}
__device__ __forceinline__ float fp8_dec1(unsigned c) {
    const unsigned s = c >> 7;
    const int e = (int)((c >> 3) & 15u);
    const unsigned m = c & 7u;
    const float v = e ? ldexpf((float)(8 + m), e - 10) : ldexpf((float)m, -9);
    return s ? -v : v;
}
#endif

// pack 4 floats -> 4 fp8 bytes in one dword
__device__ __forceinline__ unsigned fp8_pack4(float a, float b, float c, float d) {
#if HW_FP8
    int t = __builtin_amdgcn_cvt_pk_fp8_f32(a, b, 0, false);
    t     = __builtin_amdgcn_cvt_pk_fp8_f32(c, d, t, true);
    return (unsigned)t;
#else
    return fp8_enc1(a) | (fp8_enc1(b) << 8) | (fp8_enc1(c) << 16) | (fp8_enc1(d) << 24);
#endif
}

// accumulate 4 fp8 bytes (one dword) into acc[0..3]
__device__ __forceinline__ void fp8_acc4(unsigned d, float* acc) {
#if HW_FP8
    const v2f lo = __builtin_amdgcn_cvt_pk_f32_fp8((int)d, false);
    const v2f hi = __builtin_amdgcn_cvt_pk_f32_fp8((int)d, true);
    acc[0] += lo.x; acc[1] += lo.y; acc[2] += hi.x; acc[3] += hi.y;
#else
    acc[0] += fp8_dec1(d & 0xffu);
    acc[1] += fp8_dec1((d >> 8) & 0xffu);
    acc[2] += fp8_dec1((d >> 16) & 0xffu);
    acc[3] += fp8_dec1(d >> 24);
#endif
}

// x (fp32) -> fp8 gather table
__global__ __launch_bounds__(256)
void cvt_f32_fp8(const float* __restrict__ in, unsigned* __restrict__ out, int n4)
{
    int i = blockIdx.x * 256 + threadIdx.x;
    if (i < n4) {
        float4 v = ((const float4*)in)[i];
        out[i] = fp8_pack4(v.x, v.y, v.z, v.w);
    }
}

// Batcher odd-even mergesort, 16 keys, fully unrolled -> registers only.
__device__ __forceinline__ void ce(unsigned& a, unsigned& b) {
    const unsigned lo = min(a, b), hi = max(a, b); a = lo; b = hi;
}
__device__ __forceinline__ void sort16(unsigned s[16]) {
    #pragma unroll
    for (int p = 1; p < 16; p <<= 1) {
        #pragma unroll
        for (int k = p; k >= 1; k >>= 1) {
            #pragma unroll
            for (int j = k & (p - 1); j + k < 16; j += 2 * k) {
                #pragma unroll
                for (int i = 0; i < k; ++i) {
                    if (i + j + k < 16)
                        if ((i + j) / (2 * p) == (i + j + k) / (2 * p))
                            ce(s[i + j], s[i + j + k]);
                }
            }
        }
    }
}

// ---------------- fused layer: sorted fp8 gather + SGPR-W matmul ----------------
// bufA[f][n]: fp32 self features (exact path).
// bufB[kk][n]: neighbor-mean bf16 pair (features 2kk,2kk+1 of the mean half).
template<bool RELU, bool SELF_F32, bool EMIT_F32>
__global__ __launch_bounds__(256, 4)
void sage_fused(const float*  __restrict__ selfA,      // [NN,F] fp32 (if SELF_F32)
                const ushort* __restrict__ selfB,      // [NN,F] bf16 (else)
                const unsigned char* __restrict__ gat, // [NN,F] fp8 table
                const float*  __restrict__ W,          // [2F,F]
                const float*  __restrict__ bias,       // [F]
                const int*    __restrict__ src,        // [EDG]
                float*        __restrict__ out_f32,    // if EMIT_F32
                ushort*       __restrict__ out_bf16,   // else: h table (self)
                unsigned char* __restrict__ out_fp8)   // else: h table (gather)
{
    __shared__ float    bufA[F][STR];        // 16.64 KB
    __shared__ unsigned bufB[F / 2][STR];    //  8.32 KB   (25 KB total)

    const int tid   = threadIdx.x;
    const int lane  = tid & 63;
    const int wave  = __builtin_amdgcn_readfirstlane(tid >> 6);
    const int node0 = blockIdx.x * NPB;

    // ---- Self staging: lane = feature, wave stages its 16 nodes ----
    #pragma unroll 4
    for (int m = 0; m < JPW; ++m) {
        const int n    = wave * JPW + m;
        const int node = node0 + n;
        float v = 0.f;
        if (node < NN)
            v = SELF_F32 ? selfA[(size_t)node * F + lane]
                         : bf2f(selfB[(size_t)node * F + lane]);
        bufA[lane][n] = v;
    }

    // ---- Sorted fp8 gather: 4-lane group handles ONE node; dwordx4 rows ----
    // Row = 64B fp8 = one cache line: 4 lanes x 16B. R13: load ALL 16 rows
    // into a register array first (16 outstanding loads/lane), then decode.
    {
        const int q     = lane & 3;          // features 16q .. 16q+15
        const int g     = lane >> 2;         // node within wave
        const int nloc  = wave * JPW + g;
        const int n     = node0 + nloc;
        const bool v    = n < NN;

        unsigned s[DEG];
        {
            const int4* p = (const int4*)(src + (size_t)n * DEG);
            #pragma unroll
            for (int t = 0; t < 4; ++t) {
                const int4 a = v ? p[t] : make_int4(0, 0, 0, 0);
                s[4*t+0] = a.x; s[4*t+1] = a.y;
                s[4*t+2] = a.z; s[4*t+3] = a.w;
            }
        }
        sort16(s);

        // Phase 1: issue all 16 row loads (64B row = 4 lanes x 16B, 1 line).
        uint4 r[DEG];
        #pragma unroll
        for (int e = 0; e < DEG; ++e)
            r[e] = *(const uint4*)(gat + (size_t)s[e] * F + q * 16);

        // Phase 2: decode + accumulate.
        float a[16];
        #pragma unroll
        for (int f = 0; f < 16; ++f) a[f] = 0.f;
        #pragma unroll
        for (int e = 0; e < DEG; ++e) {
            fp8_acc4(r[e].x, a);
            fp8_acc4(r[e].y, a + 4);
            fp8_acc4(r[e].z, a + 8);
            fp8_acc4(r[e].w, a + 12);
        }

        // Mean -> packed bf16 pairs; kk = 8q + t covers features 16q+2t, +1.
        #pragma unroll
        for (int t = 0; t < 8; ++t) {
            const unsigned d =
                (unsigned)f2bf(a[2*t]     * (1.0f / DEG)) |
                ((unsigned)f2bf(a[2*t+1]  * (1.0f / DEG)) << 16);
            bufB[8 * q + t][nloc] = d;   // bank = (8q+t+g)%32 -> 2-way, free
        }
    }
    __syncthreads();

    // ---- Matmul: lane = node, wave owns j in [16w,16w+16) ----
    const int j0 = wave * JPW;
    float acc[JPW];
    #pragma unroll
    for (int j = 0; j < JPW; ++j) acc[j] = bias[j0 + j];   // s_load

    // Self half (fp32 LDS, exact)
    #pragma unroll 4
    for (int k = 0; k < F; ++k) {
        const float v = bufA[k][lane];           // ds_read_b32, 2-way = free
        const float* Wr = W + k * F + j0;        // wave-uniform -> s_load
        #pragma unroll
        for (int j = 0; j < JPW; ++j)
            acc[j] = fmaf(v, Wr[j], acc[j]);
    }
    // Neighbor half (packed bf16 pairs)
    #pragma unroll 2
    for (int kk = 0; kk < F / 2; ++kk) {
        const unsigned d = bufB[kk][lane];
        const float vlo = __uint_as_float(d << 16);
        const float vhi = __uint_as_float(d & 0xffff0000u);
        const float* Wlo = W + (F + 2 * kk)     * F + j0;
        const float* Whi = W + (F + 2 * kk + 1) * F + j0;
        #pragma unroll
        for (int j = 0; j < JPW; ++j) {
            acc[j] = fmaf(vlo, Wlo[j], acc[j]);
            acc[j] = fmaf(vhi, Whi[j], acc[j]);
        }
    }

    const int node = node0 + lane;
    if (node < NN) {
        if (RELU) {
            #pragma unroll
            for (int j = 0; j < JPW; ++j) acc[j] = fmaxf(acc[j], 0.f);
        }
        if (EMIT_F32) {
            float4* op = (float4*)(out_f32 + (size_t)node * F + j0);
            #pragma unroll
            for (int t = 0; t < 4; ++t)
                op[t] = make_float4(acc[4 * t], acc[4 * t + 1],
                                    acc[4 * t + 2], acc[4 * t + 3]);
        } else {
            // h tables: bf16 (self path of layer 2) + fp8 (gather table)
            uint4 q0, q1;
            #pragma unroll
            for (int t = 0; t < 8; ++t)
                (t < 4 ? (&q0.x)[t] : (&q1.x)[t - 4]) =
                    (unsigned)f2bf(acc[2 * t]) |
                    ((unsigned)f2bf(acc[2 * t + 1]) << 16);
            uint4* ob = (uint4*)(out_bf16 + (size_t)node * F + j0);
            ob[0] = q0; ob[1] = q1;

            uint4 p;
            #pragma unroll
            for (int t = 0; t < 4; ++t)
                (&p.x)[t] = fp8_pack4(acc[4*t], acc[4*t+1], acc[4*t+2], acc[4*t+3]);
            *(uint4*)(out_fp8 + (size_t)node * F + j0) = p;
        }
    }
}

// ---------------- fallback (round-3, all-fp32, fused) ----------------
template<bool RELU>
__global__ __launch_bounds__(256, 4)
void sage_layer_f32(const float* __restrict__ feat,
                    const float* __restrict__ W,
                    const float* __restrict__ bias,
                    const int*   __restrict__ src,
                    float*       __restrict__ out)
{
    __shared__ float buf[2 * F][STR];
    const int tid   = threadIdx.x;
    const int lane  = tid & 63;
    const int wave  = __builtin_amdgcn_readfirstlane(tid >> 6);
    const int node0 = blockIdx.x * NPB;

    #pragma unroll 2
    for (int m = 0; m < NPB / 4; ++m) {
        const int n    = wave * (NPB / 4) + m;
        const int node = node0 + n;
        if (node < NN) {
            buf[lane][n] = feat[node * F + lane];
            const int* sp = src + node * DEG;
            float s = 0.f;
            #pragma unroll
            for (int e = 0; e < DEG; ++e) s += feat[sp[e] * F + lane];
            buf[F + lane][n] = s * (1.0f / DEG);
        }
    }
    __syncthreads();

    const int j0 = wave * JPW;
    float acc[JPW];
    #pragma unroll
    for (int j = 0; j < JPW; ++j) acc[j] = bias[j0 + j];
    #pragma unroll 4
    for (int k = 0; k < 2 * F; ++k) {
        const float v = buf[k][lane];
        const float* Wr = W + k * F + j0;
        #pragma unroll
        for (int j = 0; j < JPW; ++j) acc[j] = fmaf(v, Wr[j], acc[j]);
    }
    const int node = node0 + lane;
    if (node < NN) {
        float4* op = (float4*)(out + node * F + j0);
        #pragma unroll
        for (int t = 0; t < 4; ++t) {
            float4 r = make_float4(acc[4 * t], acc[4 * t + 1],
                                   acc[4 * t + 2], acc[4 * t + 3]);
            if (RELU) {
                r.x = fmaxf(r.x, 0.f); r.y = fmaxf(r.y, 0.f);
                r.z = fmaxf(r.z, 0.f); r.w = fmaxf(r.w, 0.f);
            }
            op[t] = r;
        }
    }
}

extern "C" void kernel_launch(void* const* d_in, const int* in_sizes, int n_in,
                              void* d_out, int out_size, void* d_ws, size_t ws_size,
                              hipStream_t stream) {
    const float* x   = (const float*)d_in[0];
    const float* W1  = (const float*)d_in[1];
    const float* b1  = (const float*)d_in[2];
    const float* W2  = (const float*)d_in[3];
    const float* b2  = (const float*)d_in[4];
    const int*   src = (const int*)d_in[5];

    float* out = (float*)d_out;
    const int blocks = (NN + NPB - 1) / NPB;   // 1563

    const size_t hFP8 = (size_t)NN * F;                   //  6.4 MB
    const size_t hBF  = (size_t)NN * F * sizeof(ushort);  // 12.8 MB

    if (ws_size >= 2 * hFP8 + hBF) {
        unsigned char* x_fp8 = (unsigned char*)d_ws;
        ushort*        h_bf  = (ushort*)((char*)d_ws + hFP8);
        unsigned char* h_fp8 = (unsigned char*)d_ws + hFP8 + hBF;

        const int n4 = NN * F / 4;
        cvt_f32_fp8<<<(n4 + 255) / 256, 256, 0, stream>>>(x, (unsigned*)x_fp8, n4);
        sage_fused<true,  true,  false><<<blocks, 256, 0, stream>>>(
            x, nullptr, x_fp8, W1, b1, src, nullptr, h_bf, h_fp8);
        sage_fused<false, false, true ><<<blocks, 256, 0, stream>>>(
            nullptr, h_bf, h_fp8, W2, b2, src, out, nullptr, nullptr);
    } else {
        float* h = (float*)d_ws;
        sage_layer_f32<true ><<<blocks, 256, 0, stream>>>(x, W1, b1, src, h);
        sage_layer_f32<false><<<blocks, 256, 0, stream>>>(h, W2, b2, src, out);
    }
}

// Round 3
// 164.400 us; speedup vs baseline: 1.1728x; 1.0957x over previous
//
#include <hip/hip_runtime.h>

// SimpleGraphSAGE on MI355X — round 14.
// dst = repeat(arange(N),16) -> node i's edges are src[16i..16i+16), deg==16.
//
// History: R11 fp8 gather tables 70us/layer; R12 4-lane dwordx4 gather:
// 49us/layer (VGPR 40, conflicts 0); R13 batched 16-deep load window:
// REGRESSED (53us, FETCH +17% from L2 pressure) -> reverted.
// Unified cost model (R14): ~1.9 cyc per VMEM *lane-address* per CU.
// Per block: gather 4096 + self 4096 (scalar loads!) + src 1024 + out 1024.
// Self staging is as expensive as the whole gather -> vectorize it:
// fp32 self via float4 (16->4 loads/thread), bf16 self via uint4=8xbf16
// (16->2 loads/thread). LDS write patterns are 2-way bank-aliased (free).

#define NN   100000
#define DEG  16
#define F    64
#define NPB  64           // nodes per block (256 threads, 4 waves)
#define STR  65           // LDS column stride (+1 pad)
#define JPW  16           // output columns per wave
#define EDG  (NN * DEG)

#if __has_builtin(__builtin_amdgcn_cvt_pk_f32_fp8) && __has_builtin(__builtin_amdgcn_cvt_pk_fp8_f32)
#define HW_FP8 1
#else
#define HW_FP8 0
#endif

typedef float v2f __attribute__((ext_vector_type(2)));

__device__ __forceinline__ ushort f2bf(float f) {        // RNE
    unsigned u = __float_as_uint(f);
    return (ushort)((u + 0x7fffu + ((u >> 16) & 1u)) >> 16);
}
__device__ __forceinline__ float bf2f(ushort u) {
    return __uint_as_float(((unsigned)u) << 16);
}

// ---- fp8 e4m3 helpers (HW path on gfx950; manual RNE fallback) ----
#if !HW_FP8
__device__ __forceinline__ unsigned fp8_enc1(float f) {  // e4m3fn RNE, saturating
    const unsigned u = __float_as_uint(f);
    const unsigned s = (u >> 31) << 7;
    const float af = fabsf(f);
    if (!(af < 448.f)) return s | 0x7E;                  // sat (also NaN->max)
    if (af < 0.015625f) {                                // subnormal, step 2^-9
        const int n = (int)rintf(af * 512.f);            // 0..8 (8 -> min normal)
        return s | (unsigned)n;
    }
    unsigned au = u & 0x7FFFFFFFu;
    const unsigned lsb = (au >> 20) & 1u;
    au += 0x7FFFFu + lsb;                                // RNE at bit 20
    const int e = (int)(au >> 23) - 127;
    if (e > 8) return s | 0x7E;
    return s | ((unsigned)(e + 7) << 3) | ((au >> 20) & 7u);
}
__device__ __forceinline__ float fp8_dec1(unsigned c) {
    const unsigned s = c >> 7;
    const int e = (int)((c >> 3) & 15u);
    const unsigned m = c & 7u;
    const float v = e ? ldexpf((float)(8 + m), e - 10) : ldexpf((float)m, -9);
    return s ? -v : v;
}
#endif

// pack 4 floats -> 4 fp8 bytes in one dword
__device__ __forceinline__ unsigned fp8_pack4(float a, float b, float c, float d) {
#if HW_FP8
    int t = __builtin_amdgcn_cvt_pk_fp8_f32(a, b, 0, false);
    t     = __builtin_amdgcn_cvt_pk_fp8_f32(c, d, t, true);
    return (unsigned)t;
#else
    return fp8_enc1(a) | (fp8_enc1(b) << 8) | (fp8_enc1(c) << 16) | (fp8_enc1(d) << 24);
#endif
}

// accumulate 4 fp8 bytes (one dword) into acc[0..3]
__device__ __forceinline__ void fp8_acc4(unsigned d, float* acc) {
#if HW_FP8
    const v2f lo = __builtin_amdgcn_cvt_pk_f32_fp8((int)d, false);
    const v2f hi = __builtin_amdgcn_cvt_pk_f32_fp8((int)d, true);
    acc[0] += lo.x; acc[1] += lo.y; acc[2] += hi.x; acc[3] += hi.y;
#else
    acc[0] += fp8_dec1(d & 0xffu);
    acc[1] += fp8_dec1((d >> 8) & 0xffu);
    acc[2] += fp8_dec1((d >> 16) & 0xffu);
    acc[3] += fp8_dec1(d >> 24);
#endif
}

// x (fp32) -> fp8 gather table
__global__ __launch_bounds__(256)
void cvt_f32_fp8(const float* __restrict__ in, unsigned* __restrict__ out, int n4)
{
    int i = blockIdx.x * 256 + threadIdx.x;
    if (i < n4) {
        float4 v = ((const float4*)in)[i];
        out[i] = fp8_pack4(v.x, v.y, v.z, v.w);
    }
}

// Batcher odd-even mergesort, 16 keys, fully unrolled -> registers only.
__device__ __forceinline__ void ce(unsigned& a, unsigned& b) {
    const unsigned lo = min(a, b), hi = max(a, b); a = lo; b = hi;
}
__device__ __forceinline__ void sort16(unsigned s[16]) {
    #pragma unroll
    for (int p = 1; p < 16; p <<= 1) {
        #pragma unroll
        for (int k = p; k >= 1; k >>= 1) {
            #pragma unroll
            for (int j = k & (p - 1); j + k < 16; j += 2 * k) {
                #pragma unroll
                for (int i = 0; i < k; ++i) {
                    if (i + j + k < 16)
                        if ((i + j) / (2 * p) == (i + j + k) / (2 * p))
                            ce(s[i + j], s[i + j + k]);
                }
            }
        }
    }
}

// ---------------- fused layer: sorted fp8 gather + SGPR-W matmul ----------------
// bufA[f][n]: fp32 self features (exact path).
// bufB[kk][n]: neighbor-mean bf16 pair (features 2kk,2kk+1 of the mean half).
template<bool RELU, bool SELF_F32, bool EMIT_F32>
__global__ __launch_bounds__(256, 4)
void sage_fused(const float*  __restrict__ selfA,      // [NN,F] fp32 (if SELF_F32)
                const ushort* __restrict__ selfB,      // [NN,F] bf16 (else)
                const unsigned char* __restrict__ gat, // [NN,F] fp8 table
                const float*  __restrict__ W,          // [2F,F]
                const float*  __restrict__ bias,       // [F]
                const int*    __restrict__ src,        // [EDG]
                float*        __restrict__ out_f32,    // if EMIT_F32
                ushort*       __restrict__ out_bf16,   // else: h table (self)
                unsigned char* __restrict__ out_fp8)   // else: h table (gather)
{
    __shared__ float    bufA[F][STR];        // 16.64 KB
    __shared__ unsigned bufB[F / 2][STR];    //  8.32 KB   (25 KB total)

    const int tid   = threadIdx.x;
    const int lane  = tid & 63;
    const int wave  = __builtin_amdgcn_readfirstlane(tid >> 6);
    const int node0 = blockIdx.x * NPB;

    // ---- Self staging, vectorized (R14) ----
    if (SELF_F32) {
        // i = m*256 + tid -> node = i>>4, fq = i&15 (float4 within row).
        // Loads: lane-consecutive 16B -> fully coalesced, 4 lane-addr/thread.
        // ds_write bank = (4*fq + c + n) % 32 over a wave -> 2-way, free.
        #pragma unroll
        for (int m = 0; m < 4; ++m) {
            const int i    = m * 256 + tid;
            const int n    = i >> 4;
            const int fq   = i & 15;
            const int node = node0 + n;
            float4 v = make_float4(0.f, 0.f, 0.f, 0.f);
            if (node < NN)
                v = *(const float4*)(selfA + (size_t)node * F + fq * 4);
            bufA[fq * 4 + 0][n] = v.x;
            bufA[fq * 4 + 1][n] = v.y;
            bufA[fq * 4 + 2][n] = v.z;
            bufA[fq * 4 + 3][n] = v.w;
        }
    } else {
        // bf16 rows are 128B: i = m*256 + tid -> node = i>>3, oc = i&7
        // (uint4 = 8 bf16 features). 2 lane-addr/thread.
        #pragma unroll
        for (int m = 0; m < 2; ++m) {
            const int i    = m * 256 + tid;
            const int n    = i >> 3;
            const int oc   = i & 7;
            const int node = node0 + n;
            uint4 v = make_uint4(0u, 0u, 0u, 0u);
            if (node < NN)
                v = *(const uint4*)(selfB + (size_t)node * F + oc * 8);
            #pragma unroll
            for (int t = 0; t < 4; ++t) {
                const unsigned d = (&v.x)[t];
                bufA[oc * 8 + 2 * t    ][n] = __uint_as_float(d << 16);
                bufA[oc * 8 + 2 * t + 1][n] = __uint_as_float(d & 0xffff0000u);
            }
        }
    }

    // ---- Sorted fp8 gather: 4-lane group handles ONE node; dwordx4 rows ----
    // Row = 64B fp8 = one cache line: 4 lanes x 16B (R12 interleaved form;
    // R13's batched 16-deep window regressed via L2 pressure).
    {
        const int q     = lane & 3;          // features 16q .. 16q+15
        const int g     = lane >> 2;         // node within wave
        const int nloc  = wave * JPW + g;
        const int n     = node0 + nloc;
        const bool v    = n < NN;

        unsigned s[DEG];
        {
            const int4* p = (const int4*)(src + (size_t)n * DEG);
            #pragma unroll
            for (int t = 0; t < 4; ++t) {
                const int4 a = v ? p[t] : make_int4(0, 0, 0, 0);
                s[4*t+0] = a.x; s[4*t+1] = a.y;
                s[4*t+2] = a.z; s[4*t+3] = a.w;
            }
        }
        sort16(s);

        float a[16];
        #pragma unroll
        for (int f = 0; f < 16; ++f) a[f] = 0.f;

        #pragma unroll
        for (int e = 0; e < DEG; ++e) {
            // one 16B load per lane; 4 lanes cover the 64B row (1 line)
            const uint4 r = *(const uint4*)(gat + (size_t)s[e] * F + q * 16);
            fp8_acc4(r.x, a);
            fp8_acc4(r.y, a + 4);
            fp8_acc4(r.z, a + 8);
            fp8_acc4(r.w, a + 12);
        }

        // Mean -> packed bf16 pairs; kk = 8q + t covers features 16q+2t, +1.
        #pragma unroll
        for (int t = 0; t < 8; ++t) {
            const unsigned d =
                (unsigned)f2bf(a[2*t]     * (1.0f / DEG)) |
                ((unsigned)f2bf(a[2*t+1]  * (1.0f / DEG)) << 16);
            bufB[8 * q + t][nloc] = d;   // bank = (8q+t+g)%32 -> 2-way, free
        }
    }
    __syncthreads();

    // ---- Matmul: lane = node, wave owns j in [16w,16w+16) ----
    const int j0 = wave * JPW;
    float acc[JPW];
    #pragma unroll
    for (int j = 0; j < JPW; ++j) acc[j] = bias[j0 + j];   // s_load

    // Self half (fp32 LDS, exact)
    #pragma unroll 4
    for (int k = 0; k < F; ++k) {
        const float v = bufA[k][lane];           // ds_read_b32, 2-way = free
        const float* Wr = W + k * F + j0;        // wave-uniform -> s_load
        #pragma unroll
        for (int j = 0; j < JPW; ++j)
            acc[j] = fmaf(v, Wr[j], acc[j]);
    }
    // Neighbor half (packed bf16 pairs)
    #pragma unroll 2
    for (int kk = 0; kk < F / 2; ++kk) {
        const unsigned d = bufB[kk][lane];
        const float vlo = __uint_as_float(d << 16);
        const float vhi = __uint_as_float(d & 0xffff0000u);
        const float* Wlo = W + (F + 2 * kk)     * F + j0;
        const float* Whi = W + (F + 2 * kk + 1) * F + j0;
        #pragma unroll
        for (int j = 0; j < JPW; ++j) {
            acc[j] = fmaf(vlo, Wlo[j], acc[j]);
            acc[j] = fmaf(vhi, Whi[j], acc[j]);
        }
    }

    const int node = node0 + lane;
    if (node < NN) {
        if (RELU) {
            #pragma unroll
            for (int j = 0; j < JPW; ++j) acc[j] = fmaxf(acc[j], 0.f);
        }
        if (EMIT_F32) {
            float4* op = (float4*)(out_f32 + (size_t)node * F + j0);
            #pragma unroll
            for (int t = 0; t < 4; ++t)
                op[t] = make_float4(acc[4 * t], acc[4 * t + 1],
                                    acc[4 * t + 2], acc[4 * t + 3]);
        } else {
            // h tables: bf16 (self path of layer 2) + fp8 (gather table)
            uint4 q0, q1;
            #pragma unroll
            for (int t = 0; t < 8; ++t)
                (t < 4 ? (&q0.x)[t] : (&q1.x)[t - 4]) =
                    (unsigned)f2bf(acc[2 * t]) |
                    ((unsigned)f2bf(acc[2 * t + 1]) << 16);
            uint4* ob = (uint4*)(out_bf16 + (size_t)node * F + j0);
            ob[0] = q0; ob[1] = q1;

            uint4 p;
            #pragma unroll
            for (int t = 0; t < 4; ++t)
                (&p.x)[t] = fp8_pack4(acc[4*t], acc[4*t+1], acc[4*t+2], acc[4*t+3]);
            *(uint4*)(out_fp8 + (size_t)node * F + j0) = p;
        }
    }
}

// ---------------- fallback (round-3, all-fp32, fused) ----------------
template<bool RELU>
__global__ __launch_bounds__(256, 4)
void sage_layer_f32(const float* __restrict__ feat,
                    const float* __restrict__ W,
                    const float* __restrict__ bias,
                    const int*   __restrict__ src,
                    float*       __restrict__ out)
{
    __shared__ float buf[2 * F][STR];
    const int tid   = threadIdx.x;
    const int lane  = tid & 63;
    const int wave  = __builtin_amdgcn_readfirstlane(tid >> 6);
    const int node0 = blockIdx.x * NPB;

    #pragma unroll 2
    for (int m = 0; m < NPB / 4; ++m) {
        const int n    = wave * (NPB / 4) + m;
        const int node = node0 + n;
        if (node < NN) {
            buf[lane][n] = feat[node * F + lane];
            const int* sp = src + node * DEG;
            float s = 0.f;
            #pragma unroll
            for (int e = 0; e < DEG; ++e) s += feat[sp[e] * F + lane];
            buf[F + lane][n] = s * (1.0f / DEG);
        }
    }
    __syncthreads();

    const int j0 = wave * JPW;
    float acc[JPW];
    #pragma unroll
    for (int j = 0; j < JPW; ++j) acc[j] = bias[j0 + j];
    #pragma unroll 4
    for (int k = 0; k < 2 * F; ++k) {
        const float v = buf[k][lane];
        const float* Wr = W + k * F + j0;
        #pragma unroll
        for (int j = 0; j < JPW; ++j) acc[j] = fmaf(v, Wr[j], acc[j]);
    }
    const int node = node0 + lane;
    if (node < NN) {
        float4* op = (float4*)(out + node * F + j0);
        #pragma unroll
        for (int t = 0; t < 4; ++t) {
            float4 r = make_float4(acc[4 * t], acc[4 * t + 1],
                                   acc[4 * t + 2], acc[4 * t + 3]);
            if (RELU) {
                r.x = fmaxf(r.x, 0.f); r.y = fmaxf(r.y, 0.f);
                r.z = fmaxf(r.z, 0.f); r.w = fmaxf(r.w, 0.f);
            }
            op[t] = r;
        }
    }
}

extern "C" void kernel_launch(void* const* d_in, const int* in_sizes, int n_in,
                              void* d_out, int out_size, void* d_ws, size_t ws_size,
                              hipStream_t stream) {
    const float* x   = (const float*)d_in[0];
    const float* W1  = (const float*)d_in[1];
    const float* b1  = (const float*)d_in[2];
    const float* W2  = (const float*)d_in[3];
    const float* b2  = (const float*)d_in[4];
    const int*   src = (const int*)d_in[5];

    float* out = (float*)d_out;
    const int blocks = (NN + NPB - 1) / NPB;   // 1563

    const size_t hFP8 = (size_t)NN * F;                   //  6.4 MB
    const size_t hBF  = (size_t)NN * F * sizeof(ushort);  // 12.8 MB

    if (ws_size >= 2 * hFP8 + hBF) {
        unsigned char* x_fp8 = (unsigned char*)d_ws;
        ushort*        h_bf  = (ushort*)((char*)d_ws + hFP8);
        unsigned char* h_fp8 = (unsigned char*)d_ws + hFP8 + hBF;

        const int n4 = NN * F / 4;
        cvt_f32_fp8<<<(n4 + 255) / 256, 256, 0, stream>>>(x, (unsigned*)x_fp8, n4);
        sage_fused<true,  true,  false><<<blocks, 256, 0, stream>>>(
            x, nullptr, x_fp8, W1, b1, src, nullptr, h_bf, h_fp8);
        sage_fused<false, false, true ><<<blocks, 256, 0, stream>>>(
            nullptr, h_bf, h_fp8, W2, b2, src, out, nullptr, nullptr);
    } else {
        float* h = (float*)d_ws;
        sage_layer_f32<true ><<<blocks, 256, 0, stream>>>(x, W1, b1, src, h);
        sage_layer_f32<false><<<blocks, 256, 0, stream>>>(h, W2, b2, src, out);
    }
}